// Round 1
// baseline (137.322 us; speedup 1.0000x reference)
//
#include <hip/hip_runtime.h>

#define Bn 16
#define Hn 128
#define Wn 8192
#define NMAX 64
#define TILE 1024   // columns per block
#define TPB 256     // threads per block (4 cols/thread, float4 store)

// ---------------- Phase 1: xi_new (written as float32 into out chunk 1) ----
__global__ void xi_new_kernel(const int* __restrict__ xi,
                              const int* __restrict__ N,
                              float* __restrict__ out_xi) {
    int b = blockIdx.x;       // 0..15
    int i = threadIdx.x;      // 0..63
    int nb = N[b];
    int s0 = xi[(b * NMAX + i) * 2 + 0];
    int s1 = xi[(b * NMAX + i) * 2 + 1];
    int w = s1 - s0; if (w < 0) w = 0;
    bool valid = i < nb;
    int wv = valid ? w : 0;
    // inclusive scan across the 64-lane wave
    int c = wv;
    #pragma unroll
    for (int d = 1; d < 64; d <<= 1) {
        int t = __shfl_up(c, d, 64);
        if (i >= d) c += t;
    }
    int start_new = c - wv + i;
    int end_new = c + i;
    out_xi[(b * NMAX + i) * 2 + 0] = valid ? (float)start_new : 0.0f;
    out_xi[(b * NMAX + i) * 2 + 1] = valid ? (float)end_new : 0.0f;
}

// ---------------- Phase 2: packed gather into x_new ------------------------
__global__ __launch_bounds__(TPB) void compact_kernel(
    const float* __restrict__ x, const int* __restrict__ xi,
    const int* __restrict__ N, const float* __restrict__ sep_param,
    float* __restrict__ out) {
    __shared__ int s_start[NMAX];
    __shared__ int s_end[NMAX];
    __shared__ int s_src0[NMAX];
    __shared__ int s_n;

    const int blk  = blockIdx.x;
    const int tile = blk & 7;        // 8 tiles of 1024 cols per row
    const int row  = blk >> 3;       // b*H + h   (C==1)
    const int b    = row >> 7;       // row / 128
    const int tid  = threadIdx.x;

    if (tid < NMAX) {                // wave 0 computes the segment scan
        int nb = N[b];
        int s0 = xi[(b * NMAX + tid) * 2 + 0];
        int s1 = xi[(b * NMAX + tid) * 2 + 1];
        int w = s1 - s0; if (w < 0) w = 0;
        bool valid = tid < nb;
        int wv = valid ? w : 0;
        int c = wv;
        #pragma unroll
        for (int d = 1; d < 64; d <<= 1) {
            int t = __shfl_up(c, d, 64);
            if (tid >= d) c += t;
        }
        int start_new = c - wv + tid;
        int end_new = c + tid;
        s_start[tid] = valid ? start_new : 0x7FFFFFFF;  // keep array sorted
        s_end[tid]   = valid ? end_new : -1;
        s_src0[tid]  = s0;
        if (tid == 0) s_n = nb;
    }
    __syncthreads();

    const float sep = sep_param[0];
    const int nb = s_n;
    const float* __restrict__ xrow = x + (size_t)row * Wn;
    float* __restrict__ orow = out + (size_t)row * Wn;
    const int j0 = tile * TILE + tid * 4;

    float arr[4];
    #pragma unroll
    for (int k = 0; k < 4; ++k) {
        const int j = j0 + k;
        // last seg with s_start[seg] <= j  (s_start[0] == 0 always, N >= 1)
        int seg = 0;
        #pragma unroll
        for (int step = 32; step > 0; step >>= 1) {
            int cand = seg + step;
            if (cand < NMAX && s_start[cand] <= j) seg = cand;
        }
        const int s = s_start[seg];
        const int e = s_end[seg];
        float val = 0.0f;
        if (j < e) {
            int src = s_src0[seg] + (j - s);
            if (src < 0) src = 0;
            if (src > Wn - 1) src = Wn - 1;
            val = xrow[src];
        } else if (j == e && seg < nb - 1) {
            val = sep;
        }
        arr[k] = val;
    }
    *reinterpret_cast<float4*>(orow + j0) = make_float4(arr[0], arr[1], arr[2], arr[3]);
}

extern "C" void kernel_launch(void* const* d_in, const int* in_sizes, int n_in,
                              void* d_out, int out_size, void* d_ws, size_t ws_size,
                              hipStream_t stream) {
    const float* x   = (const float*)d_in[0];
    const int* xi    = (const int*)d_in[1];
    const int* N     = (const int*)d_in[2];
    const float* sep = (const float*)d_in[3];

    float* out_x  = (float*)d_out;                          // 16*1*128*8192 floats
    float* out_xi = (float*)d_out + (size_t)Bn * Hn * Wn;   // 16*64*2 values (as f32)

    xi_new_kernel<<<Bn, NMAX, 0, stream>>>(xi, N, out_xi);

    const int blocks = Bn * Hn * (Wn / TILE);               // 16384
    compact_kernel<<<blocks, TPB, 0, stream>>>(x, xi, N, sep, out_x);
}

// Round 2
// 123.082 us; speedup vs baseline: 1.1157x; 1.1157x over previous
//
#include <hip/hip_runtime.h>

#define Bn 16
#define Hn 128
#define Wn 8192
#define NMAX 64

// =====================================================================
// Phase 1: per-batch column code map + xi_new.
// code[b][j]: >=0 -> gather x[...,code]; -2 -> sep token; -1 -> zero.
// Grid: 16 batches x 8 tiles = 128 blocks, 256 threads, 4 cols/thread.
// Blocks with tile==0 also write xi_new (as float32 into out chunk 1).
// =====================================================================
__global__ __launch_bounds__(256) void code_kernel(
    const int* __restrict__ xi, const int* __restrict__ N,
    int* __restrict__ code, float* __restrict__ out_xi) {
    __shared__ int s_start[NMAX];
    __shared__ int s_end[NMAX];
    __shared__ int s_src0[NMAX];
    __shared__ int s_n;

    const int b    = blockIdx.x >> 3;
    const int tile = blockIdx.x & 7;
    const int tid  = threadIdx.x;

    if (tid < NMAX) {
        int nb = N[b];
        int s0 = xi[(b * NMAX + tid) * 2 + 0];
        int s1 = xi[(b * NMAX + tid) * 2 + 1];
        int w = s1 - s0; if (w < 0) w = 0;
        bool valid = tid < nb;
        int wv = valid ? w : 0;
        int c = wv;
        #pragma unroll
        for (int d = 1; d < 64; d <<= 1) {
            int t = __shfl_up(c, d, 64);
            if (tid >= d) c += t;
        }
        int start_new = c - wv + tid;
        int end_new = c + tid;
        s_start[tid] = valid ? start_new : 0x7FFFFFFF;  // sentinel keeps sorted
        s_end[tid]   = valid ? end_new : -1;
        s_src0[tid]  = s0;
        if (tid == 0) s_n = nb;
        if (tile == 0) {
            out_xi[(b * NMAX + tid) * 2 + 0] = valid ? (float)start_new : 0.0f;
            out_xi[(b * NMAX + tid) * 2 + 1] = valid ? (float)end_new : 0.0f;
        }
    }
    __syncthreads();

    const int nb = s_n;
    const int j0 = tile * 1024 + tid * 4;
    int out4[4];
    #pragma unroll
    for (int k = 0; k < 4; ++k) {
        const int j = j0 + k;
        int seg = 0;  // last seg with s_start[seg] <= j (s_start[0]==0 always)
        #pragma unroll
        for (int step = 32; step > 0; step >>= 1) {
            int cand = seg + step;
            if (cand < NMAX && s_start[cand] <= j) seg = cand;
        }
        const int s = s_start[seg];
        const int e = s_end[seg];
        int c;
        if (j < e) {
            int src = s_src0[seg] + (j - s);
            if (src < 0) src = 0;
            if (src > Wn - 1) src = Wn - 1;
            c = src;
        } else if (j == e && seg < nb - 1) {
            c = -2;
        } else {
            c = -1;
        }
        out4[k] = c;
    }
    *reinterpret_cast<int4*>(code + b * Wn + j0) =
        make_int4(out4[0], out4[1], out4[2], out4[3]);
}

// =====================================================================
// Phase 2: streaming gather. One block per row (2048 blocks); each
// thread handles 8 groups of 4 cols (float4), 8-way ILP.
// =====================================================================
__global__ __launch_bounds__(256) void gather_kernel(
    const float* __restrict__ x, const int* __restrict__ code,
    const float* __restrict__ sep_param, float* __restrict__ out) {
    const int row = blockIdx.x;          // b*H + h  (C==1)
    const int b   = row >> 7;
    const int tid = threadIdx.x;

    const float sep = sep_param[0];
    const float* __restrict__ xrow = x + (size_t)row * Wn;
    float* __restrict__ orow = out + (size_t)row * Wn;
    const int* __restrict__ crow = code + b * Wn;

    int4 c[8];
    #pragma unroll
    for (int g = 0; g < 8; ++g) {
        c[g] = *reinterpret_cast<const int4*>(crow + g * 1024 + tid * 4);
    }
    #pragma unroll
    for (int g = 0; g < 8; ++g) {
        float4 v;
        v.x = (c[g].x >= 0) ? xrow[c[g].x] : ((c[g].x == -2) ? sep : 0.0f);
        v.y = (c[g].y >= 0) ? xrow[c[g].y] : ((c[g].y == -2) ? sep : 0.0f);
        v.z = (c[g].z >= 0) ? xrow[c[g].z] : ((c[g].z == -2) ? sep : 0.0f);
        v.w = (c[g].w >= 0) ? xrow[c[g].w] : ((c[g].w == -2) ? sep : 0.0f);
        *reinterpret_cast<float4*>(orow + g * 1024 + tid * 4) = v;
    }
}

// =====================================================================
// Fallback (round-1 kernel) if ws is too small for the code map.
// =====================================================================
__global__ __launch_bounds__(256) void compact_kernel(
    const float* __restrict__ x, const int* __restrict__ xi,
    const int* __restrict__ N, const float* __restrict__ sep_param,
    float* __restrict__ out) {
    __shared__ int s_start[NMAX];
    __shared__ int s_end[NMAX];
    __shared__ int s_src0[NMAX];
    __shared__ int s_n;

    const int blk  = blockIdx.x;
    const int tile = blk & 7;
    const int row  = blk >> 3;
    const int b    = row >> 7;
    const int tid  = threadIdx.x;

    if (tid < NMAX) {
        int nb = N[b];
        int s0 = xi[(b * NMAX + tid) * 2 + 0];
        int s1 = xi[(b * NMAX + tid) * 2 + 1];
        int w = s1 - s0; if (w < 0) w = 0;
        bool valid = tid < nb;
        int wv = valid ? w : 0;
        int c = wv;
        #pragma unroll
        for (int d = 1; d < 64; d <<= 1) {
            int t = __shfl_up(c, d, 64);
            if (tid >= d) c += t;
        }
        s_start[tid] = valid ? (c - wv + tid) : 0x7FFFFFFF;
        s_end[tid]   = valid ? (c + tid) : -1;
        s_src0[tid]  = s0;
        if (tid == 0) s_n = nb;
    }
    __syncthreads();

    const float sep = sep_param[0];
    const int nb = s_n;
    const float* __restrict__ xrow = x + (size_t)row * Wn;
    float* __restrict__ orow = out + (size_t)row * Wn;
    const int j0 = tile * 1024 + tid * 4;

    float arr[4];
    #pragma unroll
    for (int k = 0; k < 4; ++k) {
        const int j = j0 + k;
        int seg = 0;
        #pragma unroll
        for (int step = 32; step > 0; step >>= 1) {
            int cand = seg + step;
            if (cand < NMAX && s_start[cand] <= j) seg = cand;
        }
        const int s = s_start[seg];
        const int e = s_end[seg];
        float val = 0.0f;
        if (j < e) {
            int src = s_src0[seg] + (j - s);
            if (src < 0) src = 0;
            if (src > Wn - 1) src = Wn - 1;
            val = xrow[src];
        } else if (j == e && seg < nb - 1) {
            val = sep;
        }
        arr[k] = val;
    }
    *reinterpret_cast<float4*>(orow + j0) = make_float4(arr[0], arr[1], arr[2], arr[3]);
}

__global__ void xi_new_kernel(const int* __restrict__ xi,
                              const int* __restrict__ N,
                              float* __restrict__ out_xi) {
    int b = blockIdx.x;
    int i = threadIdx.x;
    int nb = N[b];
    int s0 = xi[(b * NMAX + i) * 2 + 0];
    int s1 = xi[(b * NMAX + i) * 2 + 1];
    int w = s1 - s0; if (w < 0) w = 0;
    bool valid = i < nb;
    int wv = valid ? w : 0;
    int c = wv;
    #pragma unroll
    for (int d = 1; d < 64; d <<= 1) {
        int t = __shfl_up(c, d, 64);
        if (i >= d) c += t;
    }
    out_xi[(b * NMAX + i) * 2 + 0] = valid ? (float)(c - wv + i) : 0.0f;
    out_xi[(b * NMAX + i) * 2 + 1] = valid ? (float)(c + i) : 0.0f;
}

extern "C" void kernel_launch(void* const* d_in, const int* in_sizes, int n_in,
                              void* d_out, int out_size, void* d_ws, size_t ws_size,
                              hipStream_t stream) {
    const float* x   = (const float*)d_in[0];
    const int* xi    = (const int*)d_in[1];
    const int* N     = (const int*)d_in[2];
    const float* sep = (const float*)d_in[3];

    float* out_x  = (float*)d_out;
    float* out_xi = (float*)d_out + (size_t)Bn * Hn * Wn;

    const size_t code_bytes = (size_t)Bn * Wn * sizeof(int);
    if (ws_size >= code_bytes) {
        int* code = (int*)d_ws;
        code_kernel<<<Bn * 8, 256, 0, stream>>>(xi, N, code, out_xi);
        gather_kernel<<<Bn * Hn, 256, 0, stream>>>(x, code, sep, out_x);
    } else {
        xi_new_kernel<<<Bn, NMAX, 0, stream>>>(xi, N, out_xi);
        compact_kernel<<<Bn * Hn * 8, 256, 0, stream>>>(x, xi, N, sep, out_x);
    }
}

// Round 4
// 118.202 us; speedup vs baseline: 1.1618x; 1.0413x over previous
//
#include <hip/hip_runtime.h>

#define Bn 16
#define Hn 128
#define Wn 8192
#define NMAX 64

typedef float nt_f4 __attribute__((ext_vector_type(4)));  // native vec for nontemporal builtin

// =====================================================================
// Phase 1: per-batch column code map + xi_new.
// code[b][j]: >=0 -> gather x[...,code]; -2 -> sep token; -1 -> zero.
// Grid: 16 batches x 8 tiles = 128 blocks, 256 threads, 4 cols/thread.
// Blocks with tile==0 also write xi_new (as float32 into out chunk 1).
// =====================================================================
__global__ __launch_bounds__(256) void code_kernel(
    const int* __restrict__ xi, const int* __restrict__ N,
    int* __restrict__ code, float* __restrict__ out_xi) {
    __shared__ int s_start[NMAX];
    __shared__ int s_end[NMAX];
    __shared__ int s_src0[NMAX];
    __shared__ int s_n;

    const int b    = blockIdx.x >> 3;
    const int tile = blockIdx.x & 7;
    const int tid  = threadIdx.x;

    if (tid < NMAX) {
        int nb = N[b];
        int s0 = xi[(b * NMAX + tid) * 2 + 0];
        int s1 = xi[(b * NMAX + tid) * 2 + 1];
        int w = s1 - s0; if (w < 0) w = 0;
        bool valid = tid < nb;
        int wv = valid ? w : 0;
        int c = wv;
        #pragma unroll
        for (int d = 1; d < 64; d <<= 1) {
            int t = __shfl_up(c, d, 64);
            if (tid >= d) c += t;
        }
        int start_new = c - wv + tid;
        int end_new = c + tid;
        s_start[tid] = valid ? start_new : 0x7FFFFFFF;  // sentinel keeps sorted
        s_end[tid]   = valid ? end_new : -1;
        s_src0[tid]  = s0;
        if (tid == 0) s_n = nb;
        if (tile == 0) {
            out_xi[(b * NMAX + tid) * 2 + 0] = valid ? (float)start_new : 0.0f;
            out_xi[(b * NMAX + tid) * 2 + 1] = valid ? (float)end_new : 0.0f;
        }
    }
    __syncthreads();

    const int nb = s_n;
    const int j0 = tile * 1024 + tid * 4;
    int out4[4];
    #pragma unroll
    for (int k = 0; k < 4; ++k) {
        const int j = j0 + k;
        int seg = 0;  // last seg with s_start[seg] <= j (s_start[0]==0 always)
        #pragma unroll
        for (int step = 32; step > 0; step >>= 1) {
            int cand = seg + step;
            if (cand < NMAX && s_start[cand] <= j) seg = cand;
        }
        const int s = s_start[seg];
        const int e = s_end[seg];
        int c;
        if (j < e) {
            int src = s_src0[seg] + (j - s);
            if (src < 0) src = 0;
            if (src > Wn - 1) src = Wn - 1;
            c = src;
        } else if (j == e && seg < nb - 1) {
            c = -2;
        } else {
            c = -1;
        }
        out4[k] = c;
    }
    *reinterpret_cast<int4*>(code + b * Wn + j0) =
        make_int4(out4[0], out4[1], out4[2], out4[3]);
}

// =====================================================================
// Phase 2: LDS-staged gather. One block per row (2048 blocks).
// Stage the 32 KB source row in LDS with coalesced float4 loads, then
// gather per output column from LDS; nontemporal float4 stores.
// VMEM/thread: 8 f4 loads + 8 i4 code loads + 8 f4 stores (vs 48 scalar
// gathers previously -> TA address-throughput relief).
// =====================================================================
__global__ __launch_bounds__(256) void gather_kernel(
    const float* __restrict__ x, const int* __restrict__ code,
    const float* __restrict__ sep_param, float* __restrict__ out) {
    __shared__ float s_x[Wn];            // 32 KB

    const int row = blockIdx.x;          // b*H + h  (C==1)
    const int b   = row >> 7;
    const int tid = threadIdx.x;

    const float sep = sep_param[0];
    const float4* __restrict__ xrow4 =
        reinterpret_cast<const float4*>(x + (size_t)row * Wn);
    float* __restrict__ orow = out + (size_t)row * Wn;
    const int* __restrict__ crow = code + b * Wn;

    // ---- stage row into LDS (perfectly coalesced) ----
    float4* s_x4 = reinterpret_cast<float4*>(s_x);
    #pragma unroll
    for (int g = 0; g < 8; ++g) {
        s_x4[g * 256 + tid] = xrow4[g * 256 + tid];
    }

    // ---- load all codes up front (ILP, L2-resident: 32 KB/batch) ----
    int4 c[8];
    #pragma unroll
    for (int g = 0; g < 8; ++g) {
        c[g] = *reinterpret_cast<const int4*>(crow + g * 1024 + tid * 4);
    }
    __syncthreads();

    // ---- gather from LDS, nontemporal vector stores ----
    #pragma unroll
    for (int g = 0; g < 8; ++g) {
        nt_f4 v;
        v.x = (c[g].x >= 0) ? s_x[c[g].x] : ((c[g].x == -2) ? sep : 0.0f);
        v.y = (c[g].y >= 0) ? s_x[c[g].y] : ((c[g].y == -2) ? sep : 0.0f);
        v.z = (c[g].z >= 0) ? s_x[c[g].z] : ((c[g].z == -2) ? sep : 0.0f);
        v.w = (c[g].w >= 0) ? s_x[c[g].w] : ((c[g].w == -2) ? sep : 0.0f);
        __builtin_nontemporal_store(v,
            reinterpret_cast<nt_f4*>(orow + g * 1024 + tid * 4));
    }
}

// =====================================================================
// Fallback (round-1 style) if ws is too small for the code map.
// =====================================================================
__global__ __launch_bounds__(256) void compact_kernel(
    const float* __restrict__ x, const int* __restrict__ xi,
    const int* __restrict__ N, const float* __restrict__ sep_param,
    float* __restrict__ out) {
    __shared__ int s_start[NMAX];
    __shared__ int s_end[NMAX];
    __shared__ int s_src0[NMAX];
    __shared__ int s_n;

    const int blk  = blockIdx.x;
    const int tile = blk & 7;
    const int row  = blk >> 3;
    const int b    = row >> 7;
    const int tid  = threadIdx.x;

    if (tid < NMAX) {
        int nb = N[b];
        int s0 = xi[(b * NMAX + tid) * 2 + 0];
        int s1 = xi[(b * NMAX + tid) * 2 + 1];
        int w = s1 - s0; if (w < 0) w = 0;
        bool valid = tid < nb;
        int wv = valid ? w : 0;
        int c = wv;
        #pragma unroll
        for (int d = 1; d < 64; d <<= 1) {
            int t = __shfl_up(c, d, 64);
            if (tid >= d) c += t;
        }
        s_start[tid] = valid ? (c - wv + tid) : 0x7FFFFFFF;
        s_end[tid]   = valid ? (c + tid) : -1;
        s_src0[tid]  = s0;
        if (tid == 0) s_n = nb;
    }
    __syncthreads();

    const float sep = sep_param[0];
    const int nb = s_n;
    const float* __restrict__ xrow = x + (size_t)row * Wn;
    float* __restrict__ orow = out + (size_t)row * Wn;
    const int j0 = tile * 1024 + tid * 4;

    float arr[4];
    #pragma unroll
    for (int k = 0; k < 4; ++k) {
        const int j = j0 + k;
        int seg = 0;
        #pragma unroll
        for (int step = 32; step > 0; step >>= 1) {
            int cand = seg + step;
            if (cand < NMAX && s_start[cand] <= j) seg = cand;
        }
        const int s = s_start[seg];
        const int e = s_end[seg];
        float val = 0.0f;
        if (j < e) {
            int src = s_src0[seg] + (j - s);
            if (src < 0) src = 0;
            if (src > Wn - 1) src = Wn - 1;
            val = xrow[src];
        } else if (j == e && seg < nb - 1) {
            val = sep;
        }
        arr[k] = val;
    }
    *reinterpret_cast<float4*>(orow + j0) = make_float4(arr[0], arr[1], arr[2], arr[3]);
}

__global__ void xi_new_kernel(const int* __restrict__ xi,
                              const int* __restrict__ N,
                              float* __restrict__ out_xi) {
    int b = blockIdx.x;
    int i = threadIdx.x;
    int nb = N[b];
    int s0 = xi[(b * NMAX + i) * 2 + 0];
    int s1 = xi[(b * NMAX + i) * 2 + 1];
    int w = s1 - s0; if (w < 0) w = 0;
    bool valid = i < nb;
    int wv = valid ? w : 0;
    int c = wv;
    #pragma unroll
    for (int d = 1; d < 64; d <<= 1) {
        int t = __shfl_up(c, d, 64);
        if (i >= d) c += t;
    }
    out_xi[(b * NMAX + i) * 2 + 0] = valid ? (float)(c - wv + i) : 0.0f;
    out_xi[(b * NMAX + i) * 2 + 1] = valid ? (float)(c + i) : 0.0f;
}

extern "C" void kernel_launch(void* const* d_in, const int* in_sizes, int n_in,
                              void* d_out, int out_size, void* d_ws, size_t ws_size,
                              hipStream_t stream) {
    const float* x   = (const float*)d_in[0];
    const int* xi    = (const int*)d_in[1];
    const int* N     = (const int*)d_in[2];
    const float* sep = (const float*)d_in[3];

    float* out_x  = (float*)d_out;
    float* out_xi = (float*)d_out + (size_t)Bn * Hn * Wn;

    const size_t code_bytes = (size_t)Bn * Wn * sizeof(int);
    if (ws_size >= code_bytes) {
        int* code = (int*)d_ws;
        code_kernel<<<Bn * 8, 256, 0, stream>>>(xi, N, code, out_xi);
        gather_kernel<<<Bn * Hn, 256, 0, stream>>>(x, code, sep, out_x);
    } else {
        xi_new_kernel<<<Bn, NMAX, 0, stream>>>(xi, N, out_xi);
        compact_kernel<<<Bn * Hn * 8, 256, 0, stream>>>(x, xi, N, sep, out_x);
    }
}